// Round 5
// baseline (206.239 us; speedup 1.0000x reference)
//
#include <hip/hip_runtime.h>

// Problem constants
#define U_CNT 784   // H*W = 28*28 (both u and v extents)
#define DKH   128   // key/value head dim
#define DD    512   // input channel dim
#define NS    16    // support classes

typedef short bf16x8 __attribute__((ext_vector_type(8)));
typedef float f32x4  __attribute__((ext_vector_type(4)));

__device__ __forceinline__ unsigned short f2bf(float f) {
  unsigned u = __builtin_bit_cast(unsigned, f);
  u += 0x7fffu + ((u >> 16) & 1u);   // round-to-nearest-even
  return (unsigned short)(u >> 16);
}

// ---------------------------------------------------------------- K0: cast W
__global__ void cast_w(const float* __restrict__ Wk, const float* __restrict__ Wv,
                       unsigned short* __restrict__ Wkv) {
  int base = (blockIdx.x * 256 + threadIdx.x) * 8;
#pragma unroll
  for (int i = 0; i < 8; ++i) {
    int e = base + i;
    int ko = e >> 9, d = e & 511;
    float v = (ko < 128) ? Wk[ko * 512 + d] : Wv[(ko - 128) * 512 + d];
    Wkv[e] = f2bf(v);
  }
}

// ------------------------------------------------------------- K1: projection
// Grid (49 p-tiles, 24 images), 4 waves/block; wave computes 4 of 16 row-groups.
__global__ __launch_bounds__(256)
void proj_kernel(const float* __restrict__ query, const float* __restrict__ support,
                 const unsigned short* __restrict__ Wkv,
                 unsigned short* __restrict__ q_t, unsigned short* __restrict__ sk_t,
                 float* __restrict__ sv_t, float* __restrict__ S1p, float* __restrict__ S2p) {
  int pt = blockIdx.x;        // 0..48
  int m  = blockIdx.y;        // 0..23
  int wave = threadIdx.x >> 6;
  int l = threadIdx.x & 63;
  int col = l & 15, rowg = l >> 4;
  int p = pt * 16 + col;
  const float* X = (m < 8) ? (query + (size_t)m * DD * U_CNT)
                           : (support + (size_t)(m - 8) * DD * U_CNT);
  f32x4 acc[4];
  f32x4 zero = {0.f, 0.f, 0.f, 0.f};
#pragma unroll
  for (int rr = 0; rr < 4; ++rr) acc[rr] = zero;

  for (int ds = 0; ds < 16; ++ds) {
    int d0 = ds * 32 + rowg * 8;
    bf16x8 bfrag;
#pragma unroll
    for (int j = 0; j < 8; ++j) {
      float x = X[(size_t)(d0 + j) * U_CNT + p];
      bfrag[j] = (short)f2bf(x);
    }
#pragma unroll
    for (int rr = 0; rr < 4; ++rr) {
      int r = wave * 4 + rr;
      const bf16x8* ap = (const bf16x8*)(Wkv + (size_t)(r * 16 + col) * DD + d0);
      acc[rr] = __builtin_amdgcn_mfma_f32_16x16x32_bf16(*ap, bfrag, acc[rr], 0, 0, 0);
    }
  }

  if (m < 8) {
    if (wave < 2) {
#pragma unroll
      for (int rr = 0; rr < 4; ++rr) {
        int r = wave * 4 + rr;
        int kb = r * 16 + rowg * 4;
        const float sc = 0.08838834764831845f;  // 1/sqrt(128)
        ushort4 o;
        o.x = f2bf(acc[rr][0] * sc); o.y = f2bf(acc[rr][1] * sc);
        o.z = f2bf(acc[rr][2] * sc); o.w = f2bf(acc[rr][3] * sc);
        *(ushort4*)(q_t + (size_t)(m * U_CNT + p) * DKH + kb) = o;
      }
    } else {
      float s1 = 0.f;
#pragma unroll
      for (int rr = 0; rr < 4; ++rr) {
        int r = wave * 4 + rr;          // 8..15
#pragma unroll
        for (int j = 0; j < 4; ++j) {
          float x = acc[rr][j];
          s1 += x * x;
          x += __shfl_xor(x, 1, 64); x += __shfl_xor(x, 2, 64);
          x += __shfl_xor(x, 4, 64); x += __shfl_xor(x, 8, 64);
          if (col == 0)
            S2p[((size_t)pt * 8 + m) * DKH + (r - 8) * 16 + rowg * 4 + j] = x;
        }
      }
#pragma unroll
      for (int o = 32; o >= 1; o >>= 1) s1 += __shfl_xor(s1, o, 64);
      if (l == 0) S1p[((wave - 2) * 49 + pt) * 8 + m] = s1;
    }
  } else {
    int img = m - 8;
    if (wave < 2) {
#pragma unroll
      for (int rr = 0; rr < 4; ++rr) {
        int r = wave * 4 + rr;
        int kb = r * 16 + rowg * 4;
        ushort4 o;
        o.x = f2bf(acc[rr][0]); o.y = f2bf(acc[rr][1]);
        o.z = f2bf(acc[rr][2]); o.w = f2bf(acc[rr][3]);
        *(ushort4*)(sk_t + (size_t)(img * U_CNT + p) * DKH + kb) = o;
      }
    } else {
#pragma unroll
      for (int rr = 0; rr < 4; ++rr) {
        int r = wave * 4 + rr;
        int kb = (r - 8) * 16 + rowg * 4;
        float4 o = make_float4(acc[rr][0], acc[rr][1], acc[rr][2], acc[rr][3]);
        *(float4*)(sv_t + (size_t)(img * U_CNT + p) * DKH + kb) = o;
      }
    }
  }
}

// -------------------------------------------- K3: scores + softmax_n + sum_u
// 3136 blocks (49 vb x 8 uc x 8 b) for full residency; B-frags double-buffered
// so iter i+1's q loads overlap iter i's MFMA+softmax.
__global__ __launch_bounds__(256, 4)
void score_kernel(const unsigned short* __restrict__ q_t,
                  const unsigned short* __restrict__ sk_t,
                  float* __restrict__ w_part) {
  int bx = blockIdx.x;            // 3136 = 49 vb * 8 uc * 8 b
  int vb = bx % 49;
  int uc = (bx / 49) & 7;
  int b  = bx / 392;
  int wv = threadIdx.x >> 6;
  int l  = threadIdx.x & 63;
  int col = l & 15, rowg = l >> 4;
  int vbase = vb * 16 + wv * 4;

  bf16x8 A[4][4];
#pragma unroll
  for (int v = 0; v < 4; ++v) {
    const unsigned short* ap =
        sk_t + ((size_t)col * U_CNT + vbase + v) * DKH + rowg * 8;
#pragma unroll
    for (int s = 0; s < 4; ++s) A[v][s] = *(const bf16x8*)(ap + s * 32);
  }

  float wl[4][4];
#pragma unroll
  for (int v = 0; v < 4; ++v)
#pragma unroll
    for (int j = 0; j < 4; ++j) wl[v][j] = 0.f;

  int ut0 = (uc == 0) ? 0 : 7 + (uc - 1) * 6;   // u-tile split 7,6,6,6,6,6,6,6
  int cnt = (uc == 0) ? 7 : 6;
  const unsigned short* qb = q_t + (size_t)b * U_CNT * DKH;
  f32x4 zero = {0.f, 0.f, 0.f, 0.f};

  const unsigned short* qp0 =
      qb + (size_t)(ut0 * 16 + col) * DKH + rowg * 8;
  bf16x8 B0 = *(const bf16x8*)(qp0);
  bf16x8 B1 = *(const bf16x8*)(qp0 + 32);
  bf16x8 B2 = *(const bf16x8*)(qp0 + 64);
  bf16x8 B3 = *(const bf16x8*)(qp0 + 96);

  for (int it = 0; it < cnt; ++it) {
    // prefetch next iter's B (clamped; redundant on last iter)
    int nit = (it + 1 < cnt) ? it + 1 : it;
    const unsigned short* qp =
        qb + (size_t)((ut0 + nit) * 16 + col) * DKH + rowg * 8;
    bf16x8 N0 = *(const bf16x8*)(qp);
    bf16x8 N1 = *(const bf16x8*)(qp + 32);
    bf16x8 N2 = *(const bf16x8*)(qp + 64);
    bf16x8 N3 = *(const bf16x8*)(qp + 96);

    f32x4 acc[4];
#pragma unroll
    for (int v = 0; v < 4; ++v) acc[v] = zero;
#pragma unroll
    for (int v = 0; v < 4; ++v)
      acc[v] = __builtin_amdgcn_mfma_f32_16x16x32_bf16(A[v][0], B0, acc[v], 0, 0, 0);
#pragma unroll
    for (int v = 0; v < 4; ++v)
      acc[v] = __builtin_amdgcn_mfma_f32_16x16x32_bf16(A[v][1], B1, acc[v], 0, 0, 0);
#pragma unroll
    for (int v = 0; v < 4; ++v)
      acc[v] = __builtin_amdgcn_mfma_f32_16x16x32_bf16(A[v][2], B2, acc[v], 0, 0, 0);
#pragma unroll
    for (int v = 0; v < 4; ++v)
      acc[v] = __builtin_amdgcn_mfma_f32_16x16x32_bf16(A[v][3], B3, acc[v], 0, 0, 0);
#pragma unroll
    for (int v = 0; v < 4; ++v) {
      float e0 = __expf(acc[v][0]), e1 = __expf(acc[v][1]);
      float e2 = __expf(acc[v][2]), e3 = __expf(acc[v][3]);
      float ps = (e0 + e1) + (e2 + e3);
      ps += __shfl_xor(ps, 16, 64);
      ps += __shfl_xor(ps, 32, 64);
      float r = __builtin_amdgcn_rcpf(ps);
      wl[v][0] += e0 * r; wl[v][1] += e1 * r;
      wl[v][2] += e2 * r; wl[v][3] += e3 * r;
    }
    B0 = N0; B1 = N1; B2 = N2; B3 = N3;
  }
#pragma unroll
  for (int v = 0; v < 4; ++v)
#pragma unroll
    for (int j = 0; j < 4; ++j) {
      float x = wl[v][j];
      x += __shfl_xor(x, 1, 64); x += __shfl_xor(x, 2, 64);
      x += __shfl_xor(x, 4, 64); x += __shfl_xor(x, 8, 64);
      wl[v][j] = x;
    }
  __shared__ float wst[4][4][16];   // [wave][v_local][class]
#pragma unroll
  for (int v = 0; v < 4; ++v)
    if (col == v) {
#pragma unroll
      for (int j = 0; j < 4; ++j) wst[wv][v][rowg * 4 + j] = wl[v][j];
    }
  __syncthreads();
  int t = threadIdx.x;
  int vl = t >> 4, c = t & 15;
  w_part[(((size_t)uc * 8 + b) * U_CNT + vb * 16 + vl) * NS + c] =
      wst[vl >> 2][vl & 3][c];
}

// --------------------------- K4: a = sum_n w*sv -> per-block partials (T1p,T2p)
// 392 blocks (2 v each) so the grid covers all CUs; b-inner, sv read once.
__global__ __launch_bounds__(256)
void align_kernel(const float* __restrict__ w_part, const float* __restrict__ sv_t,
                  float* __restrict__ T1p, float* __restrict__ T2p) {
  int vt2 = blockIdx.x;   // 0..391
  int t = threadIdx.x;
  __shared__ float w_sh[2][8][16];   // [v_local][b][class]
  {
    int vl = t >> 7, b = (t >> 4) & 7, n = t & 15;
    float s = 0.f;
#pragma unroll
    for (int uc = 0; uc < 8; ++uc)
      s += w_part[(((size_t)uc * 8 + b) * U_CNT + vt2 * 2 + vl) * NS + n];
    w_sh[vl][b][n] = s;
  }
  __syncthreads();
  int k = t & 127, vl = t >> 7;
  int v = vt2 * 2 + vl;
  float a[8];
#pragma unroll
  for (int b = 0; b < 8; ++b) a[b] = 0.f;
#pragma unroll
  for (int n = 0; n < NS; ++n) {
    float s = sv_t[((size_t)n * U_CNT + v) * DKH + k];
#pragma unroll
    for (int b = 0; b < 8; ++b) a[b] += w_sh[vl][b][n] * s;
  }
  __shared__ float red[8][128];
  if (vl == 1) {
#pragma unroll
    for (int b = 0; b < 8; ++b) red[b][k] = a[b];
  }
  __syncthreads();
  if (vl == 0) {
#pragma unroll
    for (int b = 0; b < 8; ++b)
      T2p[((size_t)vt2 * 8 + b) * DKH + k] = a[b] + red[b][k];
  }
  __shared__ float sw1[4][8];
#pragma unroll
  for (int b = 0; b < 8; ++b) {
    float x = a[b] * a[b];
#pragma unroll
    for (int o = 32; o >= 1; o >>= 1) x += __shfl_xor(x, o, 64);
    if ((t & 63) == 0) sw1[t >> 6][b] = x;
  }
  __syncthreads();
  if (t < 8) T1p[vt2 * 8 + t] = sw1[0][t] + sw1[1][t] + sw1[2][t] + sw1[3][t];
}

// ------------------------------- K5a: parallel partial reduction (40 blocks)
__global__ __launch_bounds__(256)
void reduce_partials(const float* __restrict__ S1p, const float* __restrict__ T1p,
                     const float* __restrict__ S2p, const float* __restrict__ T2p,
                     float* __restrict__ S2, float* __restrict__ T2,
                     float* __restrict__ ST1) {
  __shared__ float smem[264];
  int bx = blockIdx.x, t = threadIdx.x;
  if (bx < 32) {
    int b = bx >> 2, kq = bx & 3;
    int kl = t & 31, g = t >> 5;           // 8 groups x 32 k-lanes
    int k = kq * 32 + kl;
    float s = 0.f;
    for (int w = g; w < 392; w += 8)
      s += T2p[((size_t)w * 8 + b) * DKH + k];
    smem[g * 32 + kl] = s;
    __syncthreads();
    if (t < 32) {
      float v = 0.f;
#pragma unroll
      for (int g2 = 0; g2 < 8; ++g2) v += smem[g2 * 32 + t];
      T2[b * DKH + kq * 32 + t] = v;
    }
  } else {
    int b = bx - 32;
    int k = t & 127, h = t >> 7;
    float s = 0.f;
    for (int w = h; w < 49; w += 2)
      s += S2p[((size_t)w * 8 + b) * DKH + k];
    if (h == 1) smem[k] = s;
    __syncthreads();
    if (h == 0) S2[b * DKH + k] = s + smem[k];
    float c = 0.f;
    for (int i = t; i < 98; i += 256)  c += S1p[i * 8 + b];
    for (int i = t; i < 392; i += 256) c += T1p[i * 8 + b];
#pragma unroll
    for (int o = 32; o >= 1; o >>= 1) c += __shfl_xor(c, o, 64);
    if ((t & 63) == 0) smem[256 + (t >> 6)] = c;
    __syncthreads();
    if (t == 0) ST1[b] = smem[256] + smem[257] + smem[258] + smem[259];
  }
}

// ----------------------------------------------------------------- K5b: final
__global__ void final_kernel(const float* __restrict__ S2, const float* __restrict__ T2,
                             const float* __restrict__ ST1, float* __restrict__ out) {
  int b = blockIdx.x, t = threadIdx.x;  // 128 threads
  float p = S2[b * DKH + t] * T2[b * DKH + t];
#pragma unroll
  for (int o = 32; o >= 1; o >>= 1) p += __shfl_xor(p, o, 64);
  __shared__ float s2[2];
  if ((t & 63) == 0) s2[t >> 6] = p;
  __syncthreads();
  if (t == 0)
    out[b] = (784.0f * ST1[b] - 2.0f * (s2[0] + s2[1])) * (1.0f / (784.0f * 784.0f));
}

// ----------------------------------------------------------------- launcher
extern "C" void kernel_launch(void* const* d_in, const int* in_sizes, int n_in,
                              void* d_out, int out_size, void* d_ws, size_t ws_size,
                              hipStream_t stream) {
  const float* query   = (const float*)d_in[0];
  const float* support = (const float*)d_in[1];
  const float* Wk      = (const float*)d_in[2];
  const float* Wv      = (const float*)d_in[3];
  float* out = (float*)d_out;
  char* ws = (char*)d_ws;

  // workspace layout (256B-aligned)
  unsigned short* Wkv  = (unsigned short*)(ws + 0);          //  256KB
  unsigned short* q_t  = (unsigned short*)(ws + 262144);     //  bf16 [8][784][128]
  unsigned short* sk_t = (unsigned short*)(ws + 1867776);    //  bf16 [16][784][128]
  float*          sv_t = (float*)(ws + 5079040);             //  f32  [16][784][128]
  float*          w_part = (float*)(ws + 11501568);          //  f32  [8][8][784][16] 3.21MB
  float*          S1p  = (float*)(ws + 14712832);            //  [98][8]      (4KB res)
  float*          T1p  = (float*)(ws + 14716928);            //  [392][8]     (16KB res)
  float*          S2p  = (float*)(ws + 14733312);            //  [49][8][128]  ~200KB
  float*          T2p  = (float*)(ws + 14934016);            //  [392][8][128] ~1.6MB
  float*          S2   = (float*)(ws + 16539648);            //  [8][128]
  float*          T2   = (float*)(ws + 16543744);            //  [8][128]
  float*          ST1  = (float*)(ws + 16547840);            //  [8]
  if (ws_size < (size_t)16548000) return;

  cast_w<<<64, 256, 0, stream>>>(Wk, Wv, Wkv);
  proj_kernel<<<dim3(49, 24), 256, 0, stream>>>(query, support, Wkv, q_t, sk_t, sv_t, S1p, S2p);
  score_kernel<<<3136, 256, 0, stream>>>(q_t, sk_t, w_part);
  align_kernel<<<392, 256, 0, stream>>>(w_part, sv_t, T1p, T2p);
  reduce_partials<<<40, 256, 0, stream>>>(S1p, T1p, S2p, T2p, S2, T2, ST1);
  final_kernel<<<8, 128, 0, stream>>>(S2, T2, ST1, out);
}

// Round 6
// 175.765 us; speedup vs baseline: 1.1734x; 1.1734x over previous
//
#include <hip/hip_runtime.h>

// Problem constants
#define U_CNT 784   // H*W = 28*28 (both u and v extents)
#define DKH   128   // key/value head dim
#define DD    512   // input channel dim
#define NS    16    // support classes

typedef short bf16x8 __attribute__((ext_vector_type(8)));
typedef float f32x4  __attribute__((ext_vector_type(4)));

__device__ __forceinline__ unsigned short f2bf(float f) {
  unsigned u = __builtin_bit_cast(unsigned, f);
  u += 0x7fffu + ((u >> 16) & 1u);   // round-to-nearest-even
  return (unsigned short)(u >> 16);
}

// Fragment-major layouts (bf16), so MFMA fragment loads are 64x16B contiguous:
//   sk_f[v][c(16)][class(16)][8]   : frag(v,s) @ v*2048 + (s*4+rowg)*128 + col*8
//   q_f [b][ut(49)][c(16)][ul(16)][8]: frag(ut,s) @ b*100352 + ut*2048 + (s*4+rowg)*128 + col*8

// ---------------------------------------------------------------- K0: cast W
__global__ void cast_w(const float* __restrict__ Wk, const float* __restrict__ Wv,
                       unsigned short* __restrict__ Wkv) {
  int base = (blockIdx.x * 256 + threadIdx.x) * 8;
#pragma unroll
  for (int i = 0; i < 8; ++i) {
    int e = base + i;
    int ko = e >> 9, d = e & 511;
    float v = (ko < 128) ? Wk[ko * 512 + d] : Wv[(ko - 128) * 512 + d];
    Wkv[e] = f2bf(v);
  }
}

// ------------------------------------------------------------- K1: projection
// Grid (49 p-tiles, 24 images), 4 waves/block; wave computes 4 of 16 row-groups.
__global__ __launch_bounds__(256)
void proj_kernel(const float* __restrict__ query, const float* __restrict__ support,
                 const unsigned short* __restrict__ Wkv,
                 unsigned short* __restrict__ q_f, unsigned short* __restrict__ sk_f,
                 float* __restrict__ sv_t, float* __restrict__ S1p, float* __restrict__ S2p) {
  int pt = blockIdx.x;        // 0..48
  int m  = blockIdx.y;        // 0..23
  int wave = threadIdx.x >> 6;
  int l = threadIdx.x & 63;
  int col = l & 15, rowg = l >> 4;
  int p = pt * 16 + col;
  const float* X = (m < 8) ? (query + (size_t)m * DD * U_CNT)
                           : (support + (size_t)(m - 8) * DD * U_CNT);
  f32x4 acc[4];
  f32x4 zero = {0.f, 0.f, 0.f, 0.f};
#pragma unroll
  for (int rr = 0; rr < 4; ++rr) acc[rr] = zero;

  for (int ds = 0; ds < 16; ++ds) {
    int d0 = ds * 32 + rowg * 8;
    bf16x8 bfrag;
#pragma unroll
    for (int j = 0; j < 8; ++j) {
      float x = X[(size_t)(d0 + j) * U_CNT + p];
      bfrag[j] = (short)f2bf(x);
    }
#pragma unroll
    for (int rr = 0; rr < 4; ++rr) {
      int r = wave * 4 + rr;
      const bf16x8* ap = (const bf16x8*)(Wkv + (size_t)(r * 16 + col) * DD + d0);
      acc[rr] = __builtin_amdgcn_mfma_f32_16x16x32_bf16(*ap, bfrag, acc[rr], 0, 0, 0);
    }
  }

  if (m < 8) {
    if (wave < 2) {
      // rows 0..127 -> q_f fragment-major (scaled bf16)
#pragma unroll
      for (int rr = 0; rr < 4; ++rr) {
        int r = wave * 4 + rr;          // 0..7
        const float sc = 0.08838834764831845f;  // 1/sqrt(128)
        ushort4 o;
        o.x = f2bf(acc[rr][0] * sc); o.y = f2bf(acc[rr][1] * sc);
        o.z = f2bf(acc[rr][2] * sc); o.w = f2bf(acc[rr][3] * sc);
        // c = 2r + rowg/2 ; k%8 base = (rowg&1)*4 ; ul = col
        size_t off = (size_t)m * 100352 + (size_t)pt * 2048 +
                     (size_t)(2 * r + (rowg >> 1)) * 128 + col * 8 + (rowg & 1) * 4;
        *(ushort4*)(q_f + off) = o;
      }
    } else {
      float s1 = 0.f;
#pragma unroll
      for (int rr = 0; rr < 4; ++rr) {
        int r = wave * 4 + rr;          // 8..15
#pragma unroll
        for (int j = 0; j < 4; ++j) {
          float x = acc[rr][j];
          s1 += x * x;
          x += __shfl_xor(x, 1, 64); x += __shfl_xor(x, 2, 64);
          x += __shfl_xor(x, 4, 64); x += __shfl_xor(x, 8, 64);
          if (col == 0)
            S2p[((size_t)pt * 8 + m) * DKH + (r - 8) * 16 + rowg * 4 + j] = x;
        }
      }
#pragma unroll
      for (int o = 32; o >= 1; o >>= 1) s1 += __shfl_xor(s1, o, 64);
      if (l == 0) S1p[((wave - 2) * 49 + pt) * 8 + m] = s1;
    }
  } else {
    int img = m - 8;
    if (wave < 2) {
      // rows 0..127 -> sk_f fragment-major
#pragma unroll
      for (int rr = 0; rr < 4; ++rr) {
        int r = wave * 4 + rr;          // 0..7
        ushort4 o;
        o.x = f2bf(acc[rr][0]); o.y = f2bf(acc[rr][1]);
        o.z = f2bf(acc[rr][2]); o.w = f2bf(acc[rr][3]);
        size_t off = (size_t)p * 2048 +
                     (size_t)(2 * r + (rowg >> 1)) * 128 + img * 8 + (rowg & 1) * 4;
        *(ushort4*)(sk_f + off) = o;
      }
    } else {
#pragma unroll
      for (int rr = 0; rr < 4; ++rr) {
        int r = wave * 4 + rr;
        int kb = (r - 8) * 16 + rowg * 4;
        float4 o = make_float4(acc[rr][0], acc[rr][1], acc[rr][2], acc[rr][3]);
        *(float4*)(sv_t + (size_t)(img * U_CNT + p) * DKH + kb) = o;
      }
    }
  }
}

// -------------------------------------------- K3: scores + softmax_n + sum_u
// 1568 blocks (49 vb x 4 uc x 8 b). All fragment loads are 64-lane contiguous
// 1KB transactions (fragment-major layout). B double-buffered across iters.
__global__ __launch_bounds__(256, 4)
void score_kernel(const unsigned short* __restrict__ q_f,
                  const unsigned short* __restrict__ sk_f,
                  float* __restrict__ w_part) {
  int bx = blockIdx.x;            // 1568 = 49 vb * 4 uc * 8 b
  int vb = bx % 49;
  int uc = (bx / 49) & 3;
  int b  = bx / 196;
  int wv = threadIdx.x >> 6;
  int l  = threadIdx.x & 63;
  int col = l & 15, rowg = l >> 4;
  int vbase = vb * 16 + wv * 4;

  bf16x8 A[4][4];
#pragma unroll
  for (int v = 0; v < 4; ++v) {
    const unsigned short* ap = sk_f + (size_t)(vbase + v) * 2048 + rowg * 128 + col * 8;
#pragma unroll
    for (int s = 0; s < 4; ++s) A[v][s] = *(const bf16x8*)(ap + s * 512);
  }

  float wl[4][4];
#pragma unroll
  for (int v = 0; v < 4; ++v)
#pragma unroll
    for (int j = 0; j < 4; ++j) wl[v][j] = 0.f;

  int ut0 = (uc == 0) ? 0 : uc * 12 + 1;       // u-tile split 13/12/12/12
  int cnt = (uc == 0) ? 13 : 12;
  const unsigned short* qb = q_f + (size_t)b * 100352 + rowg * 128 + col * 8;
  f32x4 zero = {0.f, 0.f, 0.f, 0.f};

  const unsigned short* qp0 = qb + (size_t)ut0 * 2048;
  bf16x8 B0 = *(const bf16x8*)(qp0);
  bf16x8 B1 = *(const bf16x8*)(qp0 + 512);
  bf16x8 B2 = *(const bf16x8*)(qp0 + 1024);
  bf16x8 B3 = *(const bf16x8*)(qp0 + 1536);

  for (int it = 0; it < cnt; ++it) {
    int nit = (it + 1 < cnt) ? it + 1 : it;
    const unsigned short* qp = qb + (size_t)(ut0 + nit) * 2048;
    bf16x8 N0 = *(const bf16x8*)(qp);
    bf16x8 N1 = *(const bf16x8*)(qp + 512);
    bf16x8 N2 = *(const bf16x8*)(qp + 1024);
    bf16x8 N3 = *(const bf16x8*)(qp + 1536);

    f32x4 acc[4];
#pragma unroll
    for (int v = 0; v < 4; ++v) acc[v] = zero;
#pragma unroll
    for (int v = 0; v < 4; ++v)
      acc[v] = __builtin_amdgcn_mfma_f32_16x16x32_bf16(A[v][0], B0, acc[v], 0, 0, 0);
#pragma unroll
    for (int v = 0; v < 4; ++v)
      acc[v] = __builtin_amdgcn_mfma_f32_16x16x32_bf16(A[v][1], B1, acc[v], 0, 0, 0);
#pragma unroll
    for (int v = 0; v < 4; ++v)
      acc[v] = __builtin_amdgcn_mfma_f32_16x16x32_bf16(A[v][2], B2, acc[v], 0, 0, 0);
#pragma unroll
    for (int v = 0; v < 4; ++v)
      acc[v] = __builtin_amdgcn_mfma_f32_16x16x32_bf16(A[v][3], B3, acc[v], 0, 0, 0);
#pragma unroll
    for (int v = 0; v < 4; ++v) {
      float e0 = __expf(acc[v][0]), e1 = __expf(acc[v][1]);
      float e2 = __expf(acc[v][2]), e3 = __expf(acc[v][3]);
      float ps = (e0 + e1) + (e2 + e3);
      ps += __shfl_xor(ps, 16, 64);
      ps += __shfl_xor(ps, 32, 64);
      float r = __builtin_amdgcn_rcpf(ps);
      wl[v][0] += e0 * r; wl[v][1] += e1 * r;
      wl[v][2] += e2 * r; wl[v][3] += e3 * r;
    }
    B0 = N0; B1 = N1; B2 = N2; B3 = N3;
  }
#pragma unroll
  for (int v = 0; v < 4; ++v)
#pragma unroll
    for (int j = 0; j < 4; ++j) {
      float x = wl[v][j];
      x += __shfl_xor(x, 1, 64); x += __shfl_xor(x, 2, 64);
      x += __shfl_xor(x, 4, 64); x += __shfl_xor(x, 8, 64);
      wl[v][j] = x;
    }
  __shared__ float wst[4][4][16];   // [wave][v_local][class]
#pragma unroll
  for (int v = 0; v < 4; ++v)
    if (col == v) {
#pragma unroll
      for (int j = 0; j < 4; ++j) wst[wv][v][rowg * 4 + j] = wl[v][j];
    }
  __syncthreads();
  int t = threadIdx.x;
  int vl = t >> 4, c = t & 15;
  w_part[(((size_t)uc * 8 + b) * U_CNT + vb * 16 + vl) * NS + c] =
      wst[vl >> 2][vl & 3][c];
}

// --------------------------- K4: a = sum_n w*sv -> per-block partials (T1p,T2p)
__global__ __launch_bounds__(256)
void align_kernel(const float* __restrict__ w_part, const float* __restrict__ sv_t,
                  float* __restrict__ T1p, float* __restrict__ T2p) {
  int vt2 = blockIdx.x;   // 0..391
  int t = threadIdx.x;
  __shared__ float w_sh[2][8][16];   // [v_local][b][class]
  {
    int vl = t >> 7, b = (t >> 4) & 7, n = t & 15;
    float s = 0.f;
#pragma unroll
    for (int uc = 0; uc < 4; ++uc)
      s += w_part[(((size_t)uc * 8 + b) * U_CNT + vt2 * 2 + vl) * NS + n];
    w_sh[vl][b][n] = s;
  }
  __syncthreads();
  int k = t & 127, vl = t >> 7;
  int v = vt2 * 2 + vl;
  float a[8];
#pragma unroll
  for (int b = 0; b < 8; ++b) a[b] = 0.f;
#pragma unroll
  for (int n = 0; n < NS; ++n) {
    float s = sv_t[((size_t)n * U_CNT + v) * DKH + k];
#pragma unroll
    for (int b = 0; b < 8; ++b) a[b] += w_sh[vl][b][n] * s;
  }
  __shared__ float red[8][128];
  if (vl == 1) {
#pragma unroll
    for (int b = 0; b < 8; ++b) red[b][k] = a[b];
  }
  __syncthreads();
  if (vl == 0) {
#pragma unroll
    for (int b = 0; b < 8; ++b)
      T2p[((size_t)vt2 * 8 + b) * DKH + k] = a[b] + red[b][k];
  }
  __shared__ float sw1[4][8];
#pragma unroll
  for (int b = 0; b < 8; ++b) {
    float x = a[b] * a[b];
#pragma unroll
    for (int o = 32; o >= 1; o >>= 1) x += __shfl_xor(x, o, 64);
    if ((t & 63) == 0) sw1[t >> 6][b] = x;
  }
  __syncthreads();
  if (t < 8) T1p[vt2 * 8 + t] = sw1[0][t] + sw1[1][t] + sw1[2][t] + sw1[3][t];
}

// ------------------------------- K5a: parallel partial reduction (40 blocks)
__global__ __launch_bounds__(256)
void reduce_partials(const float* __restrict__ S1p, const float* __restrict__ T1p,
                     const float* __restrict__ S2p, const float* __restrict__ T2p,
                     float* __restrict__ S2, float* __restrict__ T2,
                     float* __restrict__ ST1) {
  __shared__ float smem[264];
  int bx = blockIdx.x, t = threadIdx.x;
  if (bx < 32) {
    int b = bx >> 2, kq = bx & 3;
    int kl = t & 31, g = t >> 5;           // 8 groups x 32 k-lanes
    int k = kq * 32 + kl;
    float s = 0.f;
    for (int w = g; w < 392; w += 8)
      s += T2p[((size_t)w * 8 + b) * DKH + k];
    smem[g * 32 + kl] = s;
    __syncthreads();
    if (t < 32) {
      float v = 0.f;
#pragma unroll
      for (int g2 = 0; g2 < 8; ++g2) v += smem[g2 * 32 + t];
      T2[b * DKH + kq * 32 + t] = v;
    }
  } else {
    int b = bx - 32;
    int k = t & 127, h = t >> 7;
    float s = 0.f;
    for (int w = h; w < 49; w += 2)
      s += S2p[((size_t)w * 8 + b) * DKH + k];
    if (h == 1) smem[k] = s;
    __syncthreads();
    if (h == 0) S2[b * DKH + k] = s + smem[k];
    float c = 0.f;
    for (int i = t; i < 98; i += 256)  c += S1p[i * 8 + b];
    for (int i = t; i < 392; i += 256) c += T1p[i * 8 + b];
#pragma unroll
    for (int o = 32; o >= 1; o >>= 1) c += __shfl_xor(c, o, 64);
    if ((t & 63) == 0) smem[256 + (t >> 6)] = c;
    __syncthreads();
    if (t == 0) ST1[b] = smem[256] + smem[257] + smem[258] + smem[259];
  }
}

// ----------------------------------------------------------------- K5b: final
__global__ void final_kernel(const float* __restrict__ S2, const float* __restrict__ T2,
                             const float* __restrict__ ST1, float* __restrict__ out) {
  int b = blockIdx.x, t = threadIdx.x;  // 128 threads
  float p = S2[b * DKH + t] * T2[b * DKH + t];
#pragma unroll
  for (int o = 32; o >= 1; o >>= 1) p += __shfl_xor(p, o, 64);
  __shared__ float s2[2];
  if ((t & 63) == 0) s2[t >> 6] = p;
  __syncthreads();
  if (t == 0)
    out[b] = (784.0f * ST1[b] - 2.0f * (s2[0] + s2[1])) * (1.0f / (784.0f * 784.0f));
}

// ----------------------------------------------------------------- launcher
extern "C" void kernel_launch(void* const* d_in, const int* in_sizes, int n_in,
                              void* d_out, int out_size, void* d_ws, size_t ws_size,
                              hipStream_t stream) {
  const float* query   = (const float*)d_in[0];
  const float* support = (const float*)d_in[1];
  const float* Wk      = (const float*)d_in[2];
  const float* Wv      = (const float*)d_in[3];
  float* out = (float*)d_out;
  char* ws = (char*)d_ws;

  // workspace layout (256B-aligned)
  unsigned short* Wkv  = (unsigned short*)(ws + 0);          //  256KB
  unsigned short* q_f  = (unsigned short*)(ws + 262144);     //  bf16 [8][49][16][16][8] 1.53MB
  unsigned short* sk_f = (unsigned short*)(ws + 1867776);    //  bf16 [784][16][16][8]   3.06MB
  float*          sv_t = (float*)(ws + 5079040);             //  f32  [16][784][128]     6.13MB
  float*          w_part = (float*)(ws + 11501568);          //  f32  [4][8][784][16]    1.6MB
  float*          S1p  = (float*)(ws + 14712832);            //  [98][8]
  float*          T1p  = (float*)(ws + 14716928);            //  [392][8]
  float*          S2p  = (float*)(ws + 14733312);            //  [49][8][128]
  float*          T2p  = (float*)(ws + 14934016);            //  [392][8][128]
  float*          S2   = (float*)(ws + 16539648);            //  [8][128]
  float*          T2   = (float*)(ws + 16543744);            //  [8][128]
  float*          ST1  = (float*)(ws + 16547840);            //  [8]
  if (ws_size < (size_t)16548000) return;

  cast_w<<<64, 256, 0, stream>>>(Wk, Wv, Wkv);
  proj_kernel<<<dim3(49, 24), 256, 0, stream>>>(query, support, Wkv, q_f, sk_f, sv_t, S1p, S2p);
  score_kernel<<<1568, 256, 0, stream>>>(q_f, sk_f, w_part);
  align_kernel<<<392, 256, 0, stream>>>(w_part, sv_t, T1p, T2p);
  reduce_partials<<<40, 256, 0, stream>>>(S1p, T1p, S2p, T2p, S2, T2, ST1);
  final_kernel<<<8, 128, 0, stream>>>(S2, T2, ST1, out);
}

// Round 7
// 175.181 us; speedup vs baseline: 1.1773x; 1.0033x over previous
//
#include <hip/hip_runtime.h>

// Problem constants
#define U_CNT 784   // H*W = 28*28 (both u and v extents)
#define DKH   128   // key/value head dim
#define DD    512   // input channel dim
#define NS    16    // support classes

typedef short bf16x8 __attribute__((ext_vector_type(8)));
typedef float f32x4  __attribute__((ext_vector_type(4)));

__device__ __forceinline__ unsigned short f2bf(float f) {
  unsigned u = __builtin_bit_cast(unsigned, f);
  u += 0x7fffu + ((u >> 16) & 1u);   // round-to-nearest-even
  return (unsigned short)(u >> 16);
}

// Fragment-major layouts (bf16), so MFMA fragment loads are 64x16B contiguous:
//   sk_f[v][c(16)][class(16)][8]   : frag(v,s) @ v*2048 + (s*4+rowg)*128 + col*8
//   q_f [b][ut(49)][c(16)][ul(16)][8]: frag(ut,s) @ b*100352 + ut*2048 + (s*4+rowg)*128 + col*8

// ---------------------------------------------------------------- K0: cast W
__global__ void cast_w(const float* __restrict__ Wk, const float* __restrict__ Wv,
                       unsigned short* __restrict__ Wkv) {
  int base = (blockIdx.x * 256 + threadIdx.x) * 8;
#pragma unroll
  for (int i = 0; i < 8; ++i) {
    int e = base + i;
    int ko = e >> 9, d = e & 511;
    float v = (ko < 128) ? Wk[ko * 512 + d] : Wv[(ko - 128) * 512 + d];
    Wkv[e] = f2bf(v);
  }
}

// ------------------------------------------------------------- K1: projection
// Grid (49 p-tiles, 24 images). Block stages its X column-block (512d x 16p)
// into LDS transposed [p][d] with ONE coalesced pass (8 float4/thread), then
// each wave computes 4 of 16 output-row groups reading 2x ds_read_b128 per
// k-step (conflict-free). W-frags double-buffered in registers.
__global__ __launch_bounds__(256, 4)
void proj_kernel(const float* __restrict__ query, const float* __restrict__ support,
                 const unsigned short* __restrict__ Wkv,
                 unsigned short* __restrict__ q_f, unsigned short* __restrict__ sk_f,
                 float* __restrict__ sv_t, float* __restrict__ S1p, float* __restrict__ S2p) {
  constexpr int ROWW = 516;                 // padded d-row length (words) per p
  __shared__ float xs[16 * ROWW];           // 33 KB, transposed [p][d]
  int pt = blockIdx.x;        // 0..48
  int m  = blockIdx.y;        // 0..23
  int tid = threadIdx.x;
  const float* X = (m < 8) ? (query + (size_t)m * DD * U_CNT)
                           : (support + (size_t)(m - 8) * DD * U_CNT);
  int p0 = pt * 16;

  // ---- stage: 512 x 16 fp32 = 2048 float4 over 256 threads (coalesced) ----
  {
    int pi = tid & 3;          // which float4 within the 16-p row
    int dbase = tid >> 2;      // 0..63
#pragma unroll
    for (int pass = 0; pass < 8; ++pass) {
      int d = pass * 64 + dbase;
      float4 v = *(const float4*)(X + (size_t)d * U_CNT + p0 + pi * 4);
      xs[(pi * 4 + 0) * ROWW + d] = v.x;
      xs[(pi * 4 + 1) * ROWW + d] = v.y;
      xs[(pi * 4 + 2) * ROWW + d] = v.z;
      xs[(pi * 4 + 3) * ROWW + d] = v.w;
    }
  }
  __syncthreads();

  int wave = tid >> 6;
  int l = tid & 63;
  int col = l & 15, rowg = l >> 4;
  int p = p0 + col;

  f32x4 acc[4];
  f32x4 zero = {0.f, 0.f, 0.f, 0.f};
#pragma unroll
  for (int rr = 0; rr < 4; ++rr) acc[rr] = zero;

  // W-frag double buffer (A operand): rows r = wave*4+rr, lane col
  bf16x8 Acur[4], Anxt[4];
#pragma unroll
  for (int rr = 0; rr < 4; ++rr)
    Acur[rr] = *(const bf16x8*)(Wkv + (size_t)((wave * 4 + rr) * 16 + col) * DD + rowg * 8);

  for (int ds = 0; ds < 16; ++ds) {
    int nd0 = ((ds + 1) & 15) * 32 + rowg * 8;
#pragma unroll
    for (int rr = 0; rr < 4; ++rr)
      Anxt[rr] = *(const bf16x8*)(Wkv + (size_t)((wave * 4 + rr) * 16 + col) * DD + nd0);

    int d0 = ds * 32 + rowg * 8;
    const float* xp = &xs[col * ROWW + d0];
    float4 xa = *(const float4*)(xp);
    float4 xb = *(const float4*)(xp + 4);
    bf16x8 bfrag;
    bfrag[0] = (short)f2bf(xa.x); bfrag[1] = (short)f2bf(xa.y);
    bfrag[2] = (short)f2bf(xa.z); bfrag[3] = (short)f2bf(xa.w);
    bfrag[4] = (short)f2bf(xb.x); bfrag[5] = (short)f2bf(xb.y);
    bfrag[6] = (short)f2bf(xb.z); bfrag[7] = (short)f2bf(xb.w);

#pragma unroll
    for (int rr = 0; rr < 4; ++rr)
      acc[rr] = __builtin_amdgcn_mfma_f32_16x16x32_bf16(Acur[rr], bfrag, acc[rr], 0, 0, 0);
#pragma unroll
    for (int rr = 0; rr < 4; ++rr) Acur[rr] = Anxt[rr];
  }

  // ------------------------------- epilogue (unchanged from R6) -------------
  if (m < 8) {
    if (wave < 2) {
      // rows 0..127 -> q_f fragment-major (scaled bf16)
#pragma unroll
      for (int rr = 0; rr < 4; ++rr) {
        int r = wave * 4 + rr;          // 0..7
        const float sc = 0.08838834764831845f;  // 1/sqrt(128)
        ushort4 o;
        o.x = f2bf(acc[rr][0] * sc); o.y = f2bf(acc[rr][1] * sc);
        o.z = f2bf(acc[rr][2] * sc); o.w = f2bf(acc[rr][3] * sc);
        size_t off = (size_t)m * 100352 + (size_t)pt * 2048 +
                     (size_t)(2 * r + (rowg >> 1)) * 128 + col * 8 + (rowg & 1) * 4;
        *(ushort4*)(q_f + off) = o;
      }
    } else {
      float s1 = 0.f;
#pragma unroll
      for (int rr = 0; rr < 4; ++rr) {
        int r = wave * 4 + rr;          // 8..15
#pragma unroll
        for (int j = 0; j < 4; ++j) {
          float x = acc[rr][j];
          s1 += x * x;
          x += __shfl_xor(x, 1, 64); x += __shfl_xor(x, 2, 64);
          x += __shfl_xor(x, 4, 64); x += __shfl_xor(x, 8, 64);
          if (col == 0)
            S2p[((size_t)pt * 8 + m) * DKH + (r - 8) * 16 + rowg * 4 + j] = x;
        }
      }
#pragma unroll
      for (int o = 32; o >= 1; o >>= 1) s1 += __shfl_xor(s1, o, 64);
      if (l == 0) S1p[((wave - 2) * 49 + pt) * 8 + m] = s1;
    }
  } else {
    int img = m - 8;
    if (wave < 2) {
#pragma unroll
      for (int rr = 0; rr < 4; ++rr) {
        int r = wave * 4 + rr;          // 0..7
        ushort4 o;
        o.x = f2bf(acc[rr][0]); o.y = f2bf(acc[rr][1]);
        o.z = f2bf(acc[rr][2]); o.w = f2bf(acc[rr][3]);
        size_t off = (size_t)p * 2048 +
                     (size_t)(2 * r + (rowg >> 1)) * 128 + img * 8 + (rowg & 1) * 4;
        *(ushort4*)(sk_f + off) = o;
      }
    } else {
#pragma unroll
      for (int rr = 0; rr < 4; ++rr) {
        int r = wave * 4 + rr;
        int kb = (r - 8) * 16 + rowg * 4;
        float4 o = make_float4(acc[rr][0], acc[rr][1], acc[rr][2], acc[rr][3]);
        *(float4*)(sv_t + (size_t)(img * U_CNT + p) * DKH + kb) = o;
      }
    }
  }
}

// -------------------------------------------- K3: scores + softmax_n + sum_u
// 1568 blocks (49 vb x 4 uc x 8 b). All fragment loads are 64-lane contiguous
// 1KB transactions (fragment-major layout). B double-buffered across iters.
__global__ __launch_bounds__(256, 4)
void score_kernel(const unsigned short* __restrict__ q_f,
                  const unsigned short* __restrict__ sk_f,
                  float* __restrict__ w_part) {
  int bx = blockIdx.x;            // 1568 = 49 vb * 4 uc * 8 b
  int vb = bx % 49;
  int uc = (bx / 49) & 3;
  int b  = bx / 196;
  int wv = threadIdx.x >> 6;
  int l  = threadIdx.x & 63;
  int col = l & 15, rowg = l >> 4;
  int vbase = vb * 16 + wv * 4;

  bf16x8 A[4][4];
#pragma unroll
  for (int v = 0; v < 4; ++v) {
    const unsigned short* ap = sk_f + (size_t)(vbase + v) * 2048 + rowg * 128 + col * 8;
#pragma unroll
    for (int s = 0; s < 4; ++s) A[v][s] = *(const bf16x8*)(ap + s * 512);
  }

  float wl[4][4];
#pragma unroll
  for (int v = 0; v < 4; ++v)
#pragma unroll
    for (int j = 0; j < 4; ++j) wl[v][j] = 0.f;

  int ut0 = (uc == 0) ? 0 : uc * 12 + 1;       // u-tile split 13/12/12/12
  int cnt = (uc == 0) ? 13 : 12;
  const unsigned short* qb = q_f + (size_t)b * 100352 + rowg * 128 + col * 8;
  f32x4 zero = {0.f, 0.f, 0.f, 0.f};

  const unsigned short* qp0 = qb + (size_t)ut0 * 2048;
  bf16x8 B0 = *(const bf16x8*)(qp0);
  bf16x8 B1 = *(const bf16x8*)(qp0 + 512);
  bf16x8 B2 = *(const bf16x8*)(qp0 + 1024);
  bf16x8 B3 = *(const bf16x8*)(qp0 + 1536);

  for (int it = 0; it < cnt; ++it) {
    int nit = (it + 1 < cnt) ? it + 1 : it;
    const unsigned short* qp = qb + (size_t)(ut0 + nit) * 2048;
    bf16x8 N0 = *(const bf16x8*)(qp);
    bf16x8 N1 = *(const bf16x8*)(qp + 512);
    bf16x8 N2 = *(const bf16x8*)(qp + 1024);
    bf16x8 N3 = *(const bf16x8*)(qp + 1536);

    f32x4 acc[4];
#pragma unroll
    for (int v = 0; v < 4; ++v) acc[v] = zero;
#pragma unroll
    for (int v = 0; v < 4; ++v)
      acc[v] = __builtin_amdgcn_mfma_f32_16x16x32_bf16(A[v][0], B0, acc[v], 0, 0, 0);
#pragma unroll
    for (int v = 0; v < 4; ++v)
      acc[v] = __builtin_amdgcn_mfma_f32_16x16x32_bf16(A[v][1], B1, acc[v], 0, 0, 0);
#pragma unroll
    for (int v = 0; v < 4; ++v)
      acc[v] = __builtin_amdgcn_mfma_f32_16x16x32_bf16(A[v][2], B2, acc[v], 0, 0, 0);
#pragma unroll
    for (int v = 0; v < 4; ++v)
      acc[v] = __builtin_amdgcn_mfma_f32_16x16x32_bf16(A[v][3], B3, acc[v], 0, 0, 0);
#pragma unroll
    for (int v = 0; v < 4; ++v) {
      float e0 = __expf(acc[v][0]), e1 = __expf(acc[v][1]);
      float e2 = __expf(acc[v][2]), e3 = __expf(acc[v][3]);
      float ps = (e0 + e1) + (e2 + e3);
      ps += __shfl_xor(ps, 16, 64);
      ps += __shfl_xor(ps, 32, 64);
      float r = __builtin_amdgcn_rcpf(ps);
      wl[v][0] += e0 * r; wl[v][1] += e1 * r;
      wl[v][2] += e2 * r; wl[v][3] += e3 * r;
    }
    B0 = N0; B1 = N1; B2 = N2; B3 = N3;
  }
#pragma unroll
  for (int v = 0; v < 4; ++v)
#pragma unroll
    for (int j = 0; j < 4; ++j) {
      float x = wl[v][j];
      x += __shfl_xor(x, 1, 64); x += __shfl_xor(x, 2, 64);
      x += __shfl_xor(x, 4, 64); x += __shfl_xor(x, 8, 64);
      wl[v][j] = x;
    }
  __shared__ float wst[4][4][16];   // [wave][v_local][class]
#pragma unroll
  for (int v = 0; v < 4; ++v)
    if (col == v) {
#pragma unroll
      for (int j = 0; j < 4; ++j) wst[wv][v][rowg * 4 + j] = wl[v][j];
    }
  __syncthreads();
  int t = threadIdx.x;
  int vl = t >> 4, c = t & 15;
  w_part[(((size_t)uc * 8 + b) * U_CNT + vb * 16 + vl) * NS + c] =
      wst[vl >> 2][vl & 3][c];
}

// --------------------------- K4: a = sum_n w*sv -> per-block partials (T1p,T2p)
__global__ __launch_bounds__(256)
void align_kernel(const float* __restrict__ w_part, const float* __restrict__ sv_t,
                  float* __restrict__ T1p, float* __restrict__ T2p) {
  int vt2 = blockIdx.x;   // 0..391
  int t = threadIdx.x;
  __shared__ float w_sh[2][8][16];   // [v_local][b][class]
  {
    int vl = t >> 7, b = (t >> 4) & 7, n = t & 15;
    float s = 0.f;
#pragma unroll
    for (int uc = 0; uc < 4; ++uc)
      s += w_part[(((size_t)uc * 8 + b) * U_CNT + vt2 * 2 + vl) * NS + n];
    w_sh[vl][b][n] = s;
  }
  __syncthreads();
  int k = t & 127, vl = t >> 7;
  int v = vt2 * 2 + vl;
  float a[8];
#pragma unroll
  for (int b = 0; b < 8; ++b) a[b] = 0.f;
#pragma unroll
  for (int n = 0; n < NS; ++n) {
    float s = sv_t[((size_t)n * U_CNT + v) * DKH + k];
#pragma unroll
    for (int b = 0; b < 8; ++b) a[b] += w_sh[vl][b][n] * s;
  }
  __shared__ float red[8][128];
  if (vl == 1) {
#pragma unroll
    for (int b = 0; b < 8; ++b) red[b][k] = a[b];
  }
  __syncthreads();
  if (vl == 0) {
#pragma unroll
    for (int b = 0; b < 8; ++b)
      T2p[((size_t)vt2 * 8 + b) * DKH + k] = a[b] + red[b][k];
  }
  __shared__ float sw1[4][8];
#pragma unroll
  for (int b = 0; b < 8; ++b) {
    float x = a[b] * a[b];
#pragma unroll
    for (int o = 32; o >= 1; o >>= 1) x += __shfl_xor(x, o, 64);
    if ((t & 63) == 0) sw1[t >> 6][b] = x;
  }
  __syncthreads();
  if (t < 8) T1p[vt2 * 8 + t] = sw1[0][t] + sw1[1][t] + sw1[2][t] + sw1[3][t];
}

// ------------------------------- K5a: parallel partial reduction (40 blocks)
__global__ __launch_bounds__(256)
void reduce_partials(const float* __restrict__ S1p, const float* __restrict__ T1p,
                     const float* __restrict__ S2p, const float* __restrict__ T2p,
                     float* __restrict__ S2, float* __restrict__ T2,
                     float* __restrict__ ST1) {
  __shared__ float smem[264];
  int bx = blockIdx.x, t = threadIdx.x;
  if (bx < 32) {
    int b = bx >> 2, kq = bx & 3;
    int kl = t & 31, g = t >> 5;           // 8 groups x 32 k-lanes
    int k = kq * 32 + kl;
    float s = 0.f;
    for (int w = g; w < 392; w += 8)
      s += T2p[((size_t)w * 8 + b) * DKH + k];
    smem[g * 32 + kl] = s;
    __syncthreads();
    if (t < 32) {
      float v = 0.f;
#pragma unroll
      for (int g2 = 0; g2 < 8; ++g2) v += smem[g2 * 32 + t];
      T2[b * DKH + kq * 32 + t] = v;
    }
  } else {
    int b = bx - 32;
    int k = t & 127, h = t >> 7;
    float s = 0.f;
    for (int w = h; w < 49; w += 2)
      s += S2p[((size_t)w * 8 + b) * DKH + k];
    if (h == 1) smem[k] = s;
    __syncthreads();
    if (h == 0) S2[b * DKH + k] = s + smem[k];
    float c = 0.f;
    for (int i = t; i < 98; i += 256)  c += S1p[i * 8 + b];
    for (int i = t; i < 392; i += 256) c += T1p[i * 8 + b];
#pragma unroll
    for (int o = 32; o >= 1; o >>= 1) c += __shfl_xor(c, o, 64);
    if ((t & 63) == 0) smem[256 + (t >> 6)] = c;
    __syncthreads();
    if (t == 0) ST1[b] = smem[256] + smem[257] + smem[258] + smem[259];
  }
}

// ----------------------------------------------------------------- K5b: final
__global__ void final_kernel(const float* __restrict__ S2, const float* __restrict__ T2,
                             const float* __restrict__ ST1, float* __restrict__ out) {
  int b = blockIdx.x, t = threadIdx.x;  // 128 threads
  float p = S2[b * DKH + t] * T2[b * DKH + t];
#pragma unroll
  for (int o = 32; o >= 1; o >>= 1) p += __shfl_xor(p, o, 64);
  __shared__ float s2[2];
  if ((t & 63) == 0) s2[t >> 6] = p;
  __syncthreads();
  if (t == 0)
    out[b] = (784.0f * ST1[b] - 2.0f * (s2[0] + s2[1])) * (1.0f / (784.0f * 784.0f));
}

// ----------------------------------------------------------------- launcher
extern "C" void kernel_launch(void* const* d_in, const int* in_sizes, int n_in,
                              void* d_out, int out_size, void* d_ws, size_t ws_size,
                              hipStream_t stream) {
  const float* query   = (const float*)d_in[0];
  const float* support = (const float*)d_in[1];
  const float* Wk      = (const float*)d_in[2];
  const float* Wv      = (const float*)d_in[3];
  float* out = (float*)d_out;
  char* ws = (char*)d_ws;

  // workspace layout (256B-aligned)
  unsigned short* Wkv  = (unsigned short*)(ws + 0);          //  256KB
  unsigned short* q_f  = (unsigned short*)(ws + 262144);     //  bf16 [8][49][16][16][8] 1.53MB
  unsigned short* sk_f = (unsigned short*)(ws + 1867776);    //  bf16 [784][16][16][8]   3.06MB
  float*          sv_t = (float*)(ws + 5079040);             //  f32  [16][784][128]     6.13MB
  float*          w_part = (float*)(ws + 11501568);          //  f32  [4][8][784][16]    1.6MB
  float*          S1p  = (float*)(ws + 14712832);            //  [98][8]
  float*          T1p  = (float*)(ws + 14716928);            //  [392][8]
  float*          S2p  = (float*)(ws + 14733312);            //  [49][8][128]
  float*          T2p  = (float*)(ws + 14934016);            //  [392][8][128]
  float*          S2   = (float*)(ws + 16539648);            //  [8][128]
  float*          T2   = (float*)(ws + 16543744);            //  [8][128]
  float*          ST1  = (float*)(ws + 16547840);            //  [8]
  if (ws_size < (size_t)16548000) return;

  cast_w<<<64, 256, 0, stream>>>(Wk, Wv, Wkv);
  proj_kernel<<<dim3(49, 24), 256, 0, stream>>>(query, support, Wkv, q_f, sk_f, sv_t, S1p, S2p);
  score_kernel<<<1568, 256, 0, stream>>>(q_f, sk_f, w_part);
  align_kernel<<<392, 256, 0, stream>>>(w_part, sv_t, T1p, T2p);
  reduce_partials<<<40, 256, 0, stream>>>(S1p, T1p, S2p, T2p, S2, T2, ST1);
  final_kernel<<<8, 128, 0, stream>>>(S2, T2, ST1, out);
}

// Round 8
// 161.986 us; speedup vs baseline: 1.2732x; 1.0815x over previous
//
#include <hip/hip_runtime.h>

// Problem constants
#define U_CNT 784   // H*W = 28*28 (both u and v extents)
#define DKH   128   // key/value head dim
#define DD    512   // input channel dim
#define NS    16    // support classes

typedef short bf16x8 __attribute__((ext_vector_type(8)));
typedef float f32x4  __attribute__((ext_vector_type(4)));

__device__ __forceinline__ unsigned short f2bf(float f) {
  unsigned u = __builtin_bit_cast(unsigned, f);
  u += 0x7fffu + ((u >> 16) & 1u);   // round-to-nearest-even
  return (unsigned short)(u >> 16);
}

// Fragment-major layouts (bf16), so MFMA fragment loads are 64x16B contiguous:
//   sk_f[v][c(16)][class(16)][8]   : frag(v,s) @ v*2048 + (s*4+rowg)*128 + col*8
//   q_f [b][ut(49)][c(16)][ul(16)][8]: frag(ut,s) @ b*100352 + ut*2048 + (s*4+rowg)*128 + col*8

// ---------------------------------------------------------------- K0: cast W
__global__ void cast_w(const float* __restrict__ Wk, const float* __restrict__ Wv,
                       unsigned short* __restrict__ Wkv) {
  int base = (blockIdx.x * 256 + threadIdx.x) * 8;
#pragma unroll
  for (int i = 0; i < 8; ++i) {
    int e = base + i;
    int ko = e >> 9, d = e & 511;
    float v = (ko < 128) ? Wk[ko * 512 + d] : Wv[(ko - 128) * 512 + d];
    Wkv[e] = f2bf(v);
  }
}

// ------------------------------------------------------------- K1: projection
// Block = (m, pc) over 112 p => each d-row is read as a 448B contiguous window
// (7x wider than R7's 64B; fixes the ~16% HBM efficiency that bound R6/R7).
// Full K=512 in-block via 4 LDS rounds of 128d x 112p fp32, double-buffered and
// software-pipelined through a 14-float4 register stage. Per wave: 7 p-tiles x
// 4 out-row-groups (112 acc VGPRs). Compute reads = conflict-free ds_read_b128.
__global__ __launch_bounds__(256, 1)
void proj_kernel(const float* __restrict__ query, const float* __restrict__ support,
                 const unsigned short* __restrict__ Wkv,
                 unsigned short* __restrict__ q_f, unsigned short* __restrict__ sk_f,
                 float* __restrict__ sv_t, float* __restrict__ S1p, float* __restrict__ S2p) {
  constexpr int PB = 112;          // p per block
  constexpr int DR = 128;          // d per round
  constexpr int ROWW = DR + 4;     // padded LDS row (words) per p
  __shared__ float xs[2][PB * ROWW];   // 2 x 59136B
  int pc = blockIdx.x;             // 0..6
  int m  = blockIdx.y;             // 0..23
  int tid = threadIdx.x;
  int p0 = pc * PB;
  const float* X = (m < 8) ? (query + (size_t)m * DD * U_CNT)
                           : (support + (size_t)(m - 8) * DD * U_CNT);
  int drow = tid >> 1, pg = tid & 1;              // thread: half-window of one d-row
  const float* xrow = X + p0 + pg * 56;

  float4 vbuf[14];
  auto loadR = [&](int rd) {
    const float* s = xrow + (size_t)(rd * DR + drow) * U_CNT;
#pragma unroll
    for (int i = 0; i < 14; ++i) vbuf[i] = *(const float4*)(s + i * 4);
  };
  auto storeR = [&](int bb) {
    float* d0 = &xs[bb][(pg * 56) * ROWW + drow];
#pragma unroll
    for (int i = 0; i < 14; ++i) {
      float* dp = d0 + (i * 4) * ROWW;
      dp[0] = vbuf[i].x; dp[ROWW] = vbuf[i].y;
      dp[2 * ROWW] = vbuf[i].z; dp[3 * ROWW] = vbuf[i].w;
    }
  };

  int wave = tid >> 6, l = tid & 63;
  int col = l & 15, rowg = l >> 4;

  f32x4 acc[7][4];
  f32x4 zero = {0.f, 0.f, 0.f, 0.f};
#pragma unroll
  for (int v7 = 0; v7 < 7; ++v7)
#pragma unroll
    for (int rr = 0; rr < 4; ++rr) acc[v7][rr] = zero;

  loadR(0); storeR(0);
  __syncthreads();
  for (int rd = 0; rd < 4; ++rd) {
    if (rd < 3) loadR(rd + 1);        // in flight during compute
    int bb = rd & 1;
#pragma unroll
    for (int ds = 0; ds < 4; ++ds) {
      int dl = ds * 32 + rowg * 8;
      bf16x8 Af[4];
#pragma unroll
      for (int rr = 0; rr < 4; ++rr)
        Af[rr] = *(const bf16x8*)(Wkv + (size_t)((wave * 4 + rr) * 16 + col) * DD + rd * DR + dl);
#pragma unroll
      for (int v7 = 0; v7 < 7; ++v7) {
        const float* xp = &xs[bb][(v7 * 16 + col) * ROWW + dl];
        float4 xa = *(const float4*)(xp);
        float4 xb = *(const float4*)(xp + 4);
        bf16x8 bf;
        bf[0] = (short)f2bf(xa.x); bf[1] = (short)f2bf(xa.y);
        bf[2] = (short)f2bf(xa.z); bf[3] = (short)f2bf(xa.w);
        bf[4] = (short)f2bf(xb.x); bf[5] = (short)f2bf(xb.y);
        bf[6] = (short)f2bf(xb.z); bf[7] = (short)f2bf(xb.w);
#pragma unroll
        for (int rr = 0; rr < 4; ++rr)
          acc[v7][rr] = __builtin_amdgcn_mfma_f32_16x16x32_bf16(Af[rr], bf, acc[v7][rr], 0, 0, 0);
      }
    }
    if (rd < 3) {
      __syncthreads();                 // all waves done reading xs[bb^1]'s old data
      storeR((rd + 1) & 1);
      __syncthreads();                 // next round's tile visible
    }
  }

  // ------------------------------- epilogue ---------------------------------
  if (m < 8) {
    if (wave < 2) {
      // rows 0..127 -> q_f fragment-major (scaled bf16)
#pragma unroll
      for (int rr = 0; rr < 4; ++rr) {
        int r = wave * 4 + rr;          // 0..7
        const float sc = 0.08838834764831845f;  // 1/sqrt(128)
#pragma unroll
        for (int v7 = 0; v7 < 7; ++v7) {
          ushort4 o;
          o.x = f2bf(acc[v7][rr][0] * sc); o.y = f2bf(acc[v7][rr][1] * sc);
          o.z = f2bf(acc[v7][rr][2] * sc); o.w = f2bf(acc[v7][rr][3] * sc);
          size_t off = (size_t)m * 100352 + (size_t)(pc * 7 + v7) * 2048 +
                       (size_t)(2 * r + (rowg >> 1)) * 128 + col * 8 + (rowg & 1) * 4;
          *(ushort4*)(q_f + off) = o;
        }
      }
    } else {
      float s1 = 0.f;
#pragma unroll
      for (int rr = 0; rr < 4; ++rr) {
        int r = wave * 4 + rr;          // 8..15
#pragma unroll
        for (int j = 0; j < 4; ++j) {
          float xsum = 0.f;
#pragma unroll
          for (int v7 = 0; v7 < 7; ++v7) {
            float x = acc[v7][rr][j];
            s1 += x * x; xsum += x;
          }
          xsum += __shfl_xor(xsum, 1, 64); xsum += __shfl_xor(xsum, 2, 64);
          xsum += __shfl_xor(xsum, 4, 64); xsum += __shfl_xor(xsum, 8, 64);
          if (col == 0)
            S2p[((size_t)pc * 8 + m) * DKH + (r - 8) * 16 + rowg * 4 + j] = xsum;
        }
      }
#pragma unroll
      for (int o = 32; o >= 1; o >>= 1) s1 += __shfl_xor(s1, o, 64);
      if (l == 0) S1p[((wave - 2) * 7 + pc) * 8 + m] = s1;
    }
  } else {
    int img = m - 8;
    if (wave < 2) {
#pragma unroll
      for (int rr = 0; rr < 4; ++rr) {
        int r = wave * 4 + rr;          // 0..7
#pragma unroll
        for (int v7 = 0; v7 < 7; ++v7) {
          ushort4 o;
          o.x = f2bf(acc[v7][rr][0]); o.y = f2bf(acc[v7][rr][1]);
          o.z = f2bf(acc[v7][rr][2]); o.w = f2bf(acc[v7][rr][3]);
          size_t off = (size_t)(p0 + v7 * 16 + col) * 2048 +
                       (size_t)(2 * r + (rowg >> 1)) * 128 + img * 8 + (rowg & 1) * 4;
          *(ushort4*)(sk_f + off) = o;
        }
      }
    } else {
#pragma unroll
      for (int rr = 0; rr < 4; ++rr) {
        int r = wave * 4 + rr;
        int kb = (r - 8) * 16 + rowg * 4;
#pragma unroll
        for (int v7 = 0; v7 < 7; ++v7) {
          int p = p0 + v7 * 16 + col;
          float4 o = make_float4(acc[v7][rr][0], acc[v7][rr][1], acc[v7][rr][2], acc[v7][rr][3]);
          *(float4*)(sv_t + (size_t)(img * U_CNT + p) * DKH + kb) = o;
        }
      }
    }
  }
}

// -------------------------------------------- K3: scores + softmax_n + sum_u
// 1568 blocks (49 vb x 4 uc x 8 b). All fragment loads are 64-lane contiguous
// 1KB transactions (fragment-major layout). B double-buffered across iters.
__global__ __launch_bounds__(256, 4)
void score_kernel(const unsigned short* __restrict__ q_f,
                  const unsigned short* __restrict__ sk_f,
                  float* __restrict__ w_part) {
  int bx = blockIdx.x;            // 1568 = 49 vb * 4 uc * 8 b
  int vb = bx % 49;
  int uc = (bx / 49) & 3;
  int b  = bx / 196;
  int wv = threadIdx.x >> 6;
  int l  = threadIdx.x & 63;
  int col = l & 15, rowg = l >> 4;
  int vbase = vb * 16 + wv * 4;

  bf16x8 A[4][4];
#pragma unroll
  for (int v = 0; v < 4; ++v) {
    const unsigned short* ap = sk_f + (size_t)(vbase + v) * 2048 + rowg * 128 + col * 8;
#pragma unroll
    for (int s = 0; s < 4; ++s) A[v][s] = *(const bf16x8*)(ap + s * 512);
  }

  float wl[4][4];
#pragma unroll
  for (int v = 0; v < 4; ++v)
#pragma unroll
    for (int j = 0; j < 4; ++j) wl[v][j] = 0.f;

  int ut0 = (uc == 0) ? 0 : uc * 12 + 1;       // u-tile split 13/12/12/12
  int cnt = (uc == 0) ? 13 : 12;
  const unsigned short* qb = q_f + (size_t)b * 100352 + rowg * 128 + col * 8;
  f32x4 zero = {0.f, 0.f, 0.f, 0.f};

  const unsigned short* qp0 = qb + (size_t)ut0 * 2048;
  bf16x8 B0 = *(const bf16x8*)(qp0);
  bf16x8 B1 = *(const bf16x8*)(qp0 + 512);
  bf16x8 B2 = *(const bf16x8*)(qp0 + 1024);
  bf16x8 B3 = *(const bf16x8*)(qp0 + 1536);

  for (int it = 0; it < cnt; ++it) {
    int nit = (it + 1 < cnt) ? it + 1 : it;
    const unsigned short* qp = qb + (size_t)(ut0 + nit) * 2048;
    bf16x8 N0 = *(const bf16x8*)(qp);
    bf16x8 N1 = *(const bf16x8*)(qp + 512);
    bf16x8 N2 = *(const bf16x8*)(qp + 1024);
    bf16x8 N3 = *(const bf16x8*)(qp + 1536);

    f32x4 acc[4];
#pragma unroll
    for (int v = 0; v < 4; ++v) acc[v] = zero;
#pragma unroll
    for (int v = 0; v < 4; ++v)
      acc[v] = __builtin_amdgcn_mfma_f32_16x16x32_bf16(A[v][0], B0, acc[v], 0, 0, 0);
#pragma unroll
    for (int v = 0; v < 4; ++v)
      acc[v] = __builtin_amdgcn_mfma_f32_16x16x32_bf16(A[v][1], B1, acc[v], 0, 0, 0);
#pragma unroll
    for (int v = 0; v < 4; ++v)
      acc[v] = __builtin_amdgcn_mfma_f32_16x16x32_bf16(A[v][2], B2, acc[v], 0, 0, 0);
#pragma unroll
    for (int v = 0; v < 4; ++v)
      acc[v] = __builtin_amdgcn_mfma_f32_16x16x32_bf16(A[v][3], B3, acc[v], 0, 0, 0);
#pragma unroll
    for (int v = 0; v < 4; ++v) {
      float e0 = __expf(acc[v][0]), e1 = __expf(acc[v][1]);
      float e2 = __expf(acc[v][2]), e3 = __expf(acc[v][3]);
      float ps = (e0 + e1) + (e2 + e3);
      ps += __shfl_xor(ps, 16, 64);
      ps += __shfl_xor(ps, 32, 64);
      float r = __builtin_amdgcn_rcpf(ps);
      wl[v][0] += e0 * r; wl[v][1] += e1 * r;
      wl[v][2] += e2 * r; wl[v][3] += e3 * r;
    }
    B0 = N0; B1 = N1; B2 = N2; B3 = N3;
  }
#pragma unroll
  for (int v = 0; v < 4; ++v)
#pragma unroll
    for (int j = 0; j < 4; ++j) {
      float x = wl[v][j];
      x += __shfl_xor(x, 1, 64); x += __shfl_xor(x, 2, 64);
      x += __shfl_xor(x, 4, 64); x += __shfl_xor(x, 8, 64);
      wl[v][j] = x;
    }
  __shared__ float wst[4][4][16];   // [wave][v_local][class]
#pragma unroll
  for (int v = 0; v < 4; ++v)
    if (col == v) {
#pragma unroll
      for (int j = 0; j < 4; ++j) wst[wv][v][rowg * 4 + j] = wl[v][j];
    }
  __syncthreads();
  int t = threadIdx.x;
  int vl = t >> 4, c = t & 15;
  w_part[(((size_t)uc * 8 + b) * U_CNT + vb * 16 + vl) * NS + c] =
      wst[vl >> 2][vl & 3][c];
}

// --------------------------- K4: a = sum_n w*sv -> per-block partials (T1p,T2p)
__global__ __launch_bounds__(256)
void align_kernel(const float* __restrict__ w_part, const float* __restrict__ sv_t,
                  float* __restrict__ T1p, float* __restrict__ T2p) {
  int vt2 = blockIdx.x;   // 0..391
  int t = threadIdx.x;
  __shared__ float w_sh[2][8][16];   // [v_local][b][class]
  {
    int vl = t >> 7, b = (t >> 4) & 7, n = t & 15;
    float s = 0.f;
#pragma unroll
    for (int uc = 0; uc < 4; ++uc)
      s += w_part[(((size_t)uc * 8 + b) * U_CNT + vt2 * 2 + vl) * NS + n];
    w_sh[vl][b][n] = s;
  }
  __syncthreads();
  int k = t & 127, vl = t >> 7;
  int v = vt2 * 2 + vl;
  float a[8];
#pragma unroll
  for (int b = 0; b < 8; ++b) a[b] = 0.f;
#pragma unroll
  for (int n = 0; n < NS; ++n) {
    float s = sv_t[((size_t)n * U_CNT + v) * DKH + k];
#pragma unroll
    for (int b = 0; b < 8; ++b) a[b] += w_sh[vl][b][n] * s;
  }
  __shared__ float red[8][128];
  if (vl == 1) {
#pragma unroll
    for (int b = 0; b < 8; ++b) red[b][k] = a[b];
  }
  __syncthreads();
  if (vl == 0) {
#pragma unroll
    for (int b = 0; b < 8; ++b)
      T2p[((size_t)vt2 * 8 + b) * DKH + k] = a[b] + red[b][k];
  }
  __shared__ float sw1[4][8];
#pragma unroll
  for (int b = 0; b < 8; ++b) {
    float x = a[b] * a[b];
#pragma unroll
    for (int o = 32; o >= 1; o >>= 1) x += __shfl_xor(x, o, 64);
    if ((t & 63) == 0) sw1[t >> 6][b] = x;
  }
  __syncthreads();
  if (t < 8) T1p[vt2 * 8 + t] = sw1[0][t] + sw1[1][t] + sw1[2][t] + sw1[3][t];
}

// ------------------------------- K5a: parallel partial reduction (40 blocks)
__global__ __launch_bounds__(256)
void reduce_partials(const float* __restrict__ S1p, const float* __restrict__ T1p,
                     const float* __restrict__ S2p, const float* __restrict__ T2p,
                     float* __restrict__ S2, float* __restrict__ T2,
                     float* __restrict__ ST1) {
  __shared__ float smem[264];
  int bx = blockIdx.x, t = threadIdx.x;
  if (bx < 32) {
    int b = bx >> 2, kq = bx & 3;
    int kl = t & 31, g = t >> 5;           // 8 groups x 32 k-lanes
    int k = kq * 32 + kl;
    float s = 0.f;
    for (int w = g; w < 392; w += 8)
      s += T2p[((size_t)w * 8 + b) * DKH + k];
    smem[g * 32 + kl] = s;
    __syncthreads();
    if (t < 32) {
      float v = 0.f;
#pragma unroll
      for (int g2 = 0; g2 < 8; ++g2) v += smem[g2 * 32 + t];
      T2[b * DKH + kq * 32 + t] = v;
    }
  } else {
    int b = bx - 32;
    int k = t & 127, h = t >> 7;
    float s = 0.f;
    for (int w = h; w < 7; w += 2)
      s += S2p[((size_t)w * 8 + b) * DKH + k];
    if (h == 1) smem[k] = s;
    __syncthreads();
    if (h == 0) S2[b * DKH + k] = s + smem[k];
    float c = 0.f;
    for (int i = t; i < 14; i += 256)  c += S1p[i * 8 + b];
    for (int i = t; i < 392; i += 256) c += T1p[i * 8 + b];
#pragma unroll
    for (int o = 32; o >= 1; o >>= 1) c += __shfl_xor(c, o, 64);
    if ((t & 63) == 0) smem[256 + (t >> 6)] = c;
    __syncthreads();
    if (t == 0) ST1[b] = smem[256] + smem[257] + smem[258] + smem[259];
  }
}

// ----------------------------------------------------------------- K5b: final
__global__ void final_kernel(const float* __restrict__ S2, const float* __restrict__ T2,
                             const float* __restrict__ ST1, float* __restrict__ out) {
  int b = blockIdx.x, t = threadIdx.x;  // 128 threads
  float p = S2[b * DKH + t] * T2[b * DKH + t];
#pragma unroll
  for (int o = 32; o >= 1; o >>= 1) p += __shfl_xor(p, o, 64);
  __shared__ float s2[2];
  if ((t & 63) == 0) s2[t >> 6] = p;
  __syncthreads();
  if (t == 0)
    out[b] = (784.0f * ST1[b] - 2.0f * (s2[0] + s2[1])) * (1.0f / (784.0f * 784.0f));
}

// ----------------------------------------------------------------- launcher
extern "C" void kernel_launch(void* const* d_in, const int* in_sizes, int n_in,
                              void* d_out, int out_size, void* d_ws, size_t ws_size,
                              hipStream_t stream) {
  const float* query   = (const float*)d_in[0];
  const float* support = (const float*)d_in[1];
  const float* Wk      = (const float*)d_in[2];
  const float* Wv      = (const float*)d_in[3];
  float* out = (float*)d_out;
  char* ws = (char*)d_ws;

  // workspace layout (256B-aligned)
  unsigned short* Wkv  = (unsigned short*)(ws + 0);          //  256KB
  unsigned short* q_f  = (unsigned short*)(ws + 262144);     //  bf16 [8][49][16][16][8] 1.53MB
  unsigned short* sk_f = (unsigned short*)(ws + 1867776);    //  bf16 [784][16][16][8]   3.06MB
  float*          sv_t = (float*)(ws + 5079040);             //  f32  [16][784][128]     6.13MB
  float*          w_part = (float*)(ws + 11501568);          //  f32  [4][8][784][16]    1.6MB
  float*          S1p  = (float*)(ws + 14712832);            //  [14][8]
  float*          T1p  = (float*)(ws + 14716928);            //  [392][8]
  float*          S2p  = (float*)(ws + 14733312);            //  [7][8][128]
  float*          T2p  = (float*)(ws + 14934016);            //  [392][8][128]
  float*          S2   = (float*)(ws + 16539648);            //  [8][128]
  float*          T2   = (float*)(ws + 16543744);            //  [8][128]
  float*          ST1  = (float*)(ws + 16547840);            //  [8]
  if (ws_size < (size_t)16548000) return;

  cast_w<<<64, 256, 0, stream>>>(Wk, Wv, Wkv);
  proj_kernel<<<dim3(7, 24), 256, 0, stream>>>(query, support, Wkv, q_f, sk_f, sv_t, S1p, S2p);
  score_kernel<<<1568, 256, 0, stream>>>(q_f, sk_f, w_part);
  align_kernel<<<392, 256, 0, stream>>>(w_part, sv_t, T1p, T2p);
  reduce_partials<<<40, 256, 0, stream>>>(S1p, T1p, S2p, T2p, S2, T2, ST1);
  final_kernel<<<8, 128, 0, stream>>>(S2, T2, ST1, out);
}